// Round 8
// baseline (1487.307 us; speedup 1.0000x reference)
//
#include <hip/hip_runtime.h>

// Batched box-QP via ADMM (rho=1, 50 iters). One 1024-thread block per batch.
// M = Q + I (SPD) inverted in LDS by a rank-8 blocked symmetric sweep on the
// packed quad-padded lower triangle.
//
// R8: (1) XOR-swizzle tri quads (triq = q ^ ((q>>3)&7)): padded-triangle
// vertical strides are multiples of 128B -> every Schur/phase-1 vertical
// access was a ~32-way bank conflict (6.9e7 counted). Swizzle spreads bank
// phase over 8 positions. (2) Schur processes ONE column-quad at a time:
// acc = a[4] (16 regs, peak live ~40) -- fits the immovable 64-VGPR budget
// of 1024-thread blocks (R3-R7 evidence), no scratch spill. W8 dropped.

#define NX     256
#define NITER  50
#define NTHR   1024
#define NSLAB  1056
#define PTF    264

#define OFF_PT  33280
#define OFF_WT  (OFF_PT + 8 * PTF)   // 35392
#define OFF_SL  (OFF_WT + 8 * PTF)   // 37504
#define LDS_F   (OFF_SL + 72)        // 37576 floats = 150304 B

__host__ __device__ constexpr int rowoff(int r) {   // packed row offset (floats)
    return 4 * ((r >> 2) + 1) * (((r >> 2) << 1) + (r & 3));
}
__device__ __forceinline__ int physq(int q) { return q ^ ((q >> 3) & 7); }
__device__ __forceinline__ int physf(int i) { return 4 * physq(i >> 2) + (i & 3); }
// tri-region quad swizzle (bijective within aligned 8-quad groups)
__device__ __forceinline__ int triq(int q) { return q ^ ((q >> 3) & 7); }
__device__ __forceinline__ int triF(int a) { return (triq(a >> 2) << 2) | (a & 3); }

// slab s (co-major): co = max k with k*(65-k) <= s ; rq = 2co + (s - co*(65-co))
__device__ __forceinline__ void slab_coords(int s, int& rq, int& co) {
    int c = 0;
    #pragma unroll
    for (int k = 1; k < 32; ++k) c += (k * (65 - k) <= s) ? 1 : 0;
    co = c;
    rq = 2 * c + (s - c * (65 - c));
}

template <int J0>
__device__ __forceinline__ float chunk_dot(const float* tri, const float4* tri4,
                                           const float* vb, int r) {
    float acc = 0.f;
    if (r >= J0 + 63) {                 // chunk fully lower: row quads
        const int qb = (rowoff(r) >> 2) + (J0 >> 2);
        const float4* v4 = (const float4*)(vb + J0);
        #pragma unroll
        for (int m2 = 0; m2 < 16; ++m2) {
            const float4 a = tri4[triq(qb + m2)];
            const float4 v = v4[m2];
            acc += a.x * v.x + a.y * v.y + a.z * v.z + a.w * v.w;
        }
    } else if (r < J0) {                // fully upper: compile-time row offsets
        #pragma unroll
        for (int jj = 0; jj < 64; ++jj)
            acc += tri[triF(rowoff(J0 + jj) + r)] * vb[J0 + jj];
    } else {                            // mixed (few waves)
        const int ror = rowoff(r);
        #pragma unroll
        for (int jj = 0; jj < 64; ++jj) {
            const int j = J0 + jj;
            const int addr = (j <= r) ? (ror + j) : (rowoff(j) + r);
            acc += tri[triF(addr)] * vb[j];
        }
    }
    return acc;
}

__global__ void __launch_bounds__(NTHR, 1)
boxqp_r8x_kernel(const float* __restrict__ Q,
                 const float* __restrict__ p,
                 const float* __restrict__ lb,
                 const float* __restrict__ ub,
                 float* __restrict__ out)
{
    __shared__ float lds[LDS_F];
    float*  tri  = lds;
    float4* tri4 = (float4*)lds;
    float*  PT   = lds + OFF_PT;   // P transposed [8][PTF], physf-swizzled cols
    float*  WT   = lds + OFF_WT;   // W transposed [8][PTF], linear
    float*  SL   = lds + OFF_SL;   // swept pivot block [8][9] (divergence-safe)
    float*  part = lds + OFF_PT;   // matvec-phase alias (1024 f)
    float*  vbuf = lds + OFF_WT;   // matvec-phase alias (256 f)

    const int t    = threadIdx.x;
    const int lane = t & 63;
    const int b    = blockIdx.x;
    const size_t qbase = ((size_t)b) << 16;

    // --- slab assignments: s0 = t, s1 = 1024 + t (t < 32) ---
    int rq0, co0, rq1, co1;
    slab_coords(t, rq0, co0);
    const bool has2 = (t < (NSLAB - NTHR));
    slab_coords(has2 ? (NTHR + t) : 0, rq1, co1);

    // --- load lower triangle of M = Q + I, slab by slab ---
    auto load_slab = [&](int rq, int co) {
        const int r0 = rq << 2, j0q = co << 1;
        const bool dg  = ((rq >> 1) == co);      // slab touches diagonal
        const bool top = (rq == (co << 1));      // h=1 quad beyond allocation
        #pragma unroll
        for (int s2 = 0; s2 < 4; ++s2) {
            const int r  = r0 + s2;
            const int ro = rowoff(r) >> 2;
            #pragma unroll
            for (int h = 0; h < 2; ++h) {
                if (h == 1 && top) continue;
                const int gq = j0q + h;
                float4 v = *(const float4*)(Q + qbase + ((size_t)r << 8) + (gq << 2));
                if (dg) {
                    const int c0 = gq << 2;
                    v.x = (c0 + 0 > r) ? 0.f : (v.x + (c0 + 0 == r ? 1.f : 0.f));
                    v.y = (c0 + 1 > r) ? 0.f : (v.y + (c0 + 1 == r ? 1.f : 0.f));
                    v.z = (c0 + 2 > r) ? 0.f : (v.z + (c0 + 2 == r ? 1.f : 0.f));
                    v.w = (c0 + 3 > r) ? 0.f : (v.w + (c0 + 3 == r ? 1.f : 0.f));
                }
                tri4[triq(ro + gq)] = v;
            }
        }
    };
    load_slab(rq0, co0);
    if (has2) load_slab(rq1, co1);
    __syncthreads();

    // --- per-thread phase constants ---
    const int i1    = t >> 1;                    // phase-1 row (t < 512)
    const int h1    = t & 1;
    const int rowQ1 = rowoff(i1 & 255) >> 2;
    const int pfi   = physf(i1 & 255);
    const int pfT   = physf(t & 255);            // phase-2 (t < 256)

    // --- phase-3 worker (Schur / writebacks); one column-quad at a time ---
    auto update_slab = [&](int rq, int co, int kb) {
        const int r0 = rq << 2, j0q = co << 1;
        const bool top = (rq == (co << 1));
        int roQ[4];
        #pragma unroll
        for (int s2 = 0; s2 < 4; ++s2) roQ[s2] = rowoff(r0 + s2) >> 2;

        if ((rq >> 1) == kb) {
            if (co == kb) {                       // pivot block <- S (from SL)
                #pragma unroll
                for (int s2 = 0; s2 < 4; ++s2) {
                    const int sr = ((rq & 1) << 2) | s2;
                    #pragma unroll
                    for (int h = 0; h < 2; ++h) {
                        if (h == 1 && top) continue;
                        float4 v;
                        v.x = SL[sr * 9 + (h << 2) + 0];
                        v.y = SL[sr * 9 + (h << 2) + 1];
                        v.z = SL[sr * 9 + (h << 2) + 2];
                        v.w = SL[sr * 9 + (h << 2) + 3];
                        tri4[triq(roQ[s2] + j0q + h)] = v;
                    }
                }
            } else {                              // pivot rows <- W^T
                #pragma unroll
                for (int s2 = 0; s2 < 4; ++s2) {
                    const int sr = ((rq & 1) << 2) | s2;
                    float4 v0, v1;
                    v0.x = WT[sr * PTF + (j0q << 2) + 0];
                    v0.y = WT[sr * PTF + (j0q << 2) + 1];
                    v0.z = WT[sr * PTF + (j0q << 2) + 2];
                    v0.w = WT[sr * PTF + (j0q << 2) + 3];
                    v1.x = WT[sr * PTF + (j0q << 2) + 4];
                    v1.y = WT[sr * PTF + (j0q << 2) + 5];
                    v1.z = WT[sr * PTF + (j0q << 2) + 6];
                    v1.w = WT[sr * PTF + (j0q << 2) + 7];
                    tri4[triq(roQ[s2] + j0q + 0)] = v0;
                    tri4[triq(roQ[s2] + j0q + 1)] = v1;
                }
            }
        } else if (co == kb) {                    // panel <- W (read WT scalars)
            #pragma unroll
            for (int s2 = 0; s2 < 4; ++s2) {
                const int r = r0 + s2;
                float4 v0, v1;
                v0.x = WT[0 * PTF + r]; v0.y = WT[1 * PTF + r];
                v0.z = WT[2 * PTF + r]; v0.w = WT[3 * PTF + r];
                v1.x = WT[4 * PTF + r]; v1.y = WT[5 * PTF + r];
                v1.z = WT[6 * PTF + r]; v1.w = WT[7 * PTF + r];
                tri4[triq(roQ[s2] + j0q + 0)] = v0;
                tri4[triq(roQ[s2] + j0q + 1)] = v1;
            }
        } else {                                  // Schur: A -= W * P^T, per h
            #pragma unroll
            for (int h = 0; h < 2; ++h) {
                if (h == 1 && top) continue;
                const int pq = physq(j0q + h) << 2;
                float4 a[4];
                #pragma unroll
                for (int s2 = 0; s2 < 4; ++s2)
                    a[s2] = tri4[triq(roQ[s2] + j0q + h)];
                #pragma unroll
                for (int m = 0; m < 8; ++m) {
                    const float4 pa = *(const float4*)(PT + m * PTF + pq);
                    const float4 wq = *(const float4*)(WT + m * PTF + r0);
                    a[0].x -= wq.x * pa.x; a[0].y -= wq.x * pa.y;
                    a[0].z -= wq.x * pa.z; a[0].w -= wq.x * pa.w;
                    a[1].x -= wq.y * pa.x; a[1].y -= wq.y * pa.y;
                    a[1].z -= wq.y * pa.z; a[1].w -= wq.y * pa.w;
                    a[2].x -= wq.z * pa.x; a[2].y -= wq.z * pa.y;
                    a[2].z -= wq.z * pa.z; a[2].w -= wq.z * pa.w;
                    a[3].x -= wq.w * pa.x; a[3].y -= wq.w * pa.y;
                    a[3].z -= wq.w * pa.z; a[3].w -= wq.w * pa.w;
                }
                #pragma unroll
                for (int s2 = 0; s2 < 4; ++s2)
                    tri4[triq(roQ[s2] + j0q + h)] = a[s2];
            }
        }
    };

    // --- rank-8 blocked sweep: 32 steps; tri becomes -(M^{-1}) ---
    for (int kb = 0; kb < 32; ++kb) {
        const int k0 = kb << 3;

        // phase 1: snapshot panel P[i][0..7] -> PT (transposed, swizzled)
        if (t < 512) {
            const int i = i1;
            float v0, v1, v2, v3;
            if (i >= k0 + 8) {
                const float4 v = tri4[triq(rowQ1 + (kb << 1) + h1)];
                v0 = v.x; v1 = v.y; v2 = v.z; v3 = v.w;
            } else {
                const int roi = rowoff(i);
                const int km  = k0 + (h1 << 2);
                v0 = (km + 0 <= i) ? tri[triF(roi + km + 0)] : tri[triF(rowoff(km + 0) + i)];
                v1 = (km + 1 <= i) ? tri[triF(roi + km + 1)] : tri[triF(rowoff(km + 1) + i)];
                v2 = (km + 2 <= i) ? tri[triF(roi + km + 2)] : tri[triF(rowoff(km + 2) + i)];
                v3 = (km + 3 <= i) ? tri[triF(roi + km + 3)] : tri[triF(rowoff(km + 3) + i)];
            }
            const int rb = (h1 << 2) * PTF + pfi;
            PT[rb + 0 * PTF] = v0;
            PT[rb + 1 * PTF] = v1;
            PT[rb + 2 * PTF] = v2;
            PT[rb + 3 * PTF] = v3;
        }
        __syncthreads();

        // every wave (all lanes active): sweep the 8x8 pivot block in-register
        float S;
        {
            const int a = lane >> 3, bb = lane & 7;
            S = PT[bb * PTF + physf(k0 + a)];
            #pragma unroll
            for (int kk = 0; kk < 8; ++kk) {
                const float dkk = __shfl(S, kk * 9);
                const float inv = 1.0f / dkk;
                const float cs  = __shfl(S, (lane & 56) | kk);
                const float rs  = __shfl(S, (kk << 3) | bb);
                const float upd = S - cs * rs * inv;
                const bool ad = (a == kk), bd = (bb == kk);
                S = (ad && bd) ? -inv : (ad ? rs * inv : (bd ? cs * inv : upd));
            }
        }
        // wave 0 (fully active) publishes S for divergent consumers
        if (t < 64) SL[(lane >> 3) * 9 + (lane & 7)] = S;

        // phase 2 (t<256, waves 0-3 fully active -> shfl safe):
        // W[i][:] = -(P[i]·S) -> WT (transposed)
        if (t < 256) {
            float pv[8];
            #pragma unroll
            for (int m = 0; m < 8; ++m) pv[m] = PT[m * PTF + pfT];
            #pragma unroll
            for (int c = 0; c < 8; ++c) {
                float acc = 0.f;
                #pragma unroll
                for (int m = 0; m < 8; ++m) acc += pv[m] * __shfl(S, (m << 3) | c);
                WT[c * PTF + t] = -acc;
            }
        }
        __syncthreads();   // SL, WT ready

        // phase 3: per-slab update
        update_slab(rq0, co0, kb);
        if (has2) update_slab(rq1, co1, kb);
        __syncthreads();
    }

    // --- ADMM iterations: x = tri·vbuf (tri = -Minv, vbuf = u+p-z = -rhs) ---
    const int mr = t & 255;   // row handled in dot phase
    const int q4 = t >> 8;    // wave-uniform chunk id

    float x = 0.f, z = 0.f, uu = 0.f;
    float pi = 0.f, lbi = 0.f, ubi = 0.f;
    if (t < 256) {
        const int gb = (b << 8) + t;
        pi = p[gb]; lbi = lb[gb]; ubi = ub[gb];
        vbuf[t] = pi;                       // z=u=0 -> vbuf = p
    }
    __syncthreads();

    for (int it = 0; it < NITER; ++it) {
        float acc;
        switch (q4) {
            case 0:  acc = chunk_dot<0  >(tri, tri4, vbuf, mr); break;
            case 1:  acc = chunk_dot<64 >(tri, tri4, vbuf, mr); break;
            case 2:  acc = chunk_dot<128>(tri, tri4, vbuf, mr); break;
            default: acc = chunk_dot<192>(tri, tri4, vbuf, mr); break;
        }
        part[(q4 << 8) | mr] = acc;
        __syncthreads();
        if (t < 256) {
            x = part[t] + part[256 + t] + part[512 + t] + part[768 + t];
            const float xu = x + uu;
            z  = fminf(fmaxf(xu, lbi), ubi);
            uu = xu - z;
            vbuf[t] = (uu + pi) - z;
        }
        __syncthreads();
    }

    if (t < 256) out[(b << 8) + t] = x;
}

extern "C" void kernel_launch(void* const* d_in, const int* in_sizes, int n_in,
                              void* d_out, int out_size, void* d_ws, size_t ws_size,
                              hipStream_t stream) {
    const float* Q  = (const float*)d_in[0];
    const float* p  = (const float*)d_in[1];
    const float* lb = (const float*)d_in[2];
    const float* ub = (const float*)d_in[3];
    float* out = (float*)d_out;

    hipLaunchKernelGGL(boxqp_r8x_kernel, dim3(256), dim3(NTHR), 0, stream,
                       Q, p, lb, ub, out);
}

// Round 9
// 666.028 us; speedup vs baseline: 2.2331x; 2.2331x over previous
//
#include <hip/hip_runtime.h>

// Batched box-QP via ADMM (rho=1, 50 iters). ONE 256-THREAD block per batch.
// Rationale (R3-R8 evidence): 1024-thread blocks always get a 64-VGPR budget
// on this toolchain and spill to scratch (0.8-2.5 GB HBM traffic/dispatch).
// 256-thread blocks measured at 160 VGPRs with zero scratch (R1). All phases
// redesigned for 256 threads; latency hidden by per-thread ILP (4 slabs).
//
// M = Q + I (SPD) inverted in LDS by a rank-8 blocked symmetric sweep on the
// packed quad-padded lower triangle (triq XOR-swizzled). Pivot 8x8 block swept
// per-wave in registers (shfl, all lanes active), published via SL (LDS) for
// divergent consumers (R7 fix). Matvec: thread = full row, wave-uniform chunk
// branches, double-buffered rhs, 1 barrier/iter.

#define NX     256
#define NITER  50
#define NTHR   256
#define NSLAB  1056
#define PTF    264

#define OFF_PT  33280
#define OFF_WT  (OFF_PT + 8 * PTF)   // 35392
#define OFF_SL  (OFF_WT + 8 * PTF)   // 37504
#define OFF_VB  (OFF_SL + 72)        // 37576  (vbuf[2][256])
#define LDS_F   (OFF_VB + 512)       // 38088 floats = 152352 B

__host__ __device__ constexpr int rowoff(int r) {   // packed row offset (floats)
    return 4 * ((r >> 2) + 1) * (((r >> 2) << 1) + (r & 3));
}
__device__ __forceinline__ int physq(int q) { return q ^ ((q >> 3) & 7); }
__device__ __forceinline__ int physf(int i) { return 4 * physq(i >> 2) + (i & 3); }
// triangle quad swizzle (involution within aligned 8-quad groups)
__device__ __forceinline__ int triq(int q) { return q ^ ((q >> 3) & 7); }
__device__ __forceinline__ int triF(int a) { return (triq(a >> 2) << 2) | (a & 3); }

// slab s (co-major): co = max k with k*(65-k) <= s ; rq = 2co + (s - co*(65-co))
__device__ __forceinline__ void slab_coords(int s, int& rq, int& co) {
    int c = 0;
    #pragma unroll
    for (int k = 1; k < 32; ++k) c += (k * (65 - k) <= s) ? 1 : 0;
    co = c;
    rq = 2 * c + (s - c * (65 - c));
}

template <int J0>
__device__ __forceinline__ float chunk_lower(const float4* tri4, const float* vb, int r) {
    const int qb = (rowoff(r) >> 2) + (J0 >> 2);
    float a0 = 0.f, a1 = 0.f, a2 = 0.f, a3 = 0.f;
    #pragma unroll
    for (int m = 0; m < 16; ++m) {
        const float4 a = tri4[triq(qb + m)];
        const float4 v = *(const float4*)(vb + J0 + 4 * m);
        a0 += a.x * v.x; a1 += a.y * v.y; a2 += a.z * v.z; a3 += a.w * v.w;
    }
    return (a0 + a1) + (a2 + a3);
}
template <int J0>
__device__ __forceinline__ float chunk_upper(const float* tri, const float* vb, int r) {
    float a[4] = {0.f, 0.f, 0.f, 0.f};
    #pragma unroll
    for (int jj = 0; jj < 64; ++jj)   // addr = const + r: lane-consecutive
        a[jj & 3] += tri[triF(rowoff(J0 + jj) + r)] * vb[J0 + jj];
    return (a[0] + a[1]) + (a[2] + a[3]);
}
template <int J0>
__device__ __forceinline__ float chunk_mixed(const float* tri, const float* vb, int r) {
    const int ror = rowoff(r);
    float a[4] = {0.f, 0.f, 0.f, 0.f};
    #pragma unroll
    for (int jj = 0; jj < 64; ++jj) {
        const int j = J0 + jj;
        const int addr = (j <= r) ? (ror + j) : (rowoff(j) + r);
        a[jj & 3] += tri[triF(addr)] * vb[j];
    }
    return (a[0] + a[1]) + (a[2] + a[3]);
}

__global__ void __launch_bounds__(NTHR, 1)
boxqp_r9_kernel(const float* __restrict__ Q,
                const float* __restrict__ p,
                const float* __restrict__ lb,
                const float* __restrict__ ub,
                float* __restrict__ out)
{
    __shared__ __align__(16) float lds[LDS_F];
    float*  tri  = lds;
    float4* tri4 = (float4*)lds;
    float*  PT   = lds + OFF_PT;   // P transposed [8][PTF], physf-swizzled cols
    float*  WT   = lds + OFF_WT;   // W transposed [8][PTF]
    float*  SL   = lds + OFF_SL;   // swept pivot block [8][9]
    float*  vbuf = lds + OFF_VB;   // rhs double buffer [2][256]
    unsigned char* qrow = (unsigned char*)(lds + OFF_PT);  // load-phase alias

    const int t    = threadIdx.x;
    const int lane = t & 63;
    const int b    = blockIdx.x;
    const size_t qbase = ((size_t)b) << 16;

    // --- per-thread slab descriptors (registers, computed once) ---
    int rqk[5], cok[5];
    #pragma unroll
    for (int k = 0; k < 4; ++k) slab_coords(t + (k << 8), rqk[k], cok[k]);
    slab_coords((t < 32) ? (1024 + t) : 0, rqk[4], cok[4]);

    // --- qrow LUT: packed-quad index -> row (one-time; aliases PT region) ---
    {
        const int bq = rowoff(t) >> 2, nq = (t >> 2) + 1;
        for (int m = 0; m < nq; ++m) qrow[bq + m] = (unsigned char)t;
    }
    __syncthreads();

    // --- coalesced load: lower triangle of M = Q + I into swizzled tri ---
    for (int q = t; q < 8320; q += NTHR) {
        const int r  = qrow[q];
        const int ro = rowoff(r) >> 2;
        const int cq = q - ro;                  // quad index within row
        float4 v = *(const float4*)(Q + qbase + ((size_t)r << 8) + (cq << 2));
        if (cq == (r >> 2)) {                   // diagonal quad: zero upper, +1
            const int c0 = cq << 2;
            v.x = (c0 + 0 > r) ? 0.f : (v.x + (c0 + 0 == r ? 1.f : 0.f));
            v.y = (c0 + 1 > r) ? 0.f : (v.y + (c0 + 1 == r ? 1.f : 0.f));
            v.z = (c0 + 2 > r) ? 0.f : (v.z + (c0 + 2 == r ? 1.f : 0.f));
            v.w = (c0 + 3 > r) ? 0.f : (v.w + (c0 + 3 == r ? 1.f : 0.f));
        }
        tri4[triq(q)] = v;
    }
    __syncthreads();

    const int roQt = rowoff(t) >> 2;
    const int pft  = physf(t);

    // --- phase-3 worker (Schur / writebacks) ---
    auto update_slab = [&](int rq, int co, int kb) {
        const int r0 = rq << 2, j0q = co << 1;
        const bool top = (rq == (co << 1));
        int roQ[4];
        #pragma unroll
        for (int s2 = 0; s2 < 4; ++s2) roQ[s2] = rowoff(r0 + s2) >> 2;

        if ((rq >> 1) == kb) {
            if (co == kb) {                       // pivot block <- S (from SL)
                #pragma unroll
                for (int s2 = 0; s2 < 4; ++s2) {
                    const int sr = ((rq & 1) << 2) | s2;
                    #pragma unroll
                    for (int h = 0; h < 2; ++h) {
                        if (h == 1 && top) continue;
                        float4 v;
                        v.x = SL[sr * 9 + (h << 2) + 0];
                        v.y = SL[sr * 9 + (h << 2) + 1];
                        v.z = SL[sr * 9 + (h << 2) + 2];
                        v.w = SL[sr * 9 + (h << 2) + 3];
                        tri4[triq(roQ[s2] + j0q + h)] = v;
                    }
                }
            } else {                              // pivot rows <- W^T
                #pragma unroll
                for (int s2 = 0; s2 < 4; ++s2) {
                    const int sr = ((rq & 1) << 2) | s2;
                    const int jb = j0q << 2;
                    float4 v0, v1;
                    v0.x = WT[sr * PTF + jb + 0]; v0.y = WT[sr * PTF + jb + 1];
                    v0.z = WT[sr * PTF + jb + 2]; v0.w = WT[sr * PTF + jb + 3];
                    v1.x = WT[sr * PTF + jb + 4]; v1.y = WT[sr * PTF + jb + 5];
                    v1.z = WT[sr * PTF + jb + 6]; v1.w = WT[sr * PTF + jb + 7];
                    tri4[triq(roQ[s2] + j0q + 0)] = v0;
                    tri4[triq(roQ[s2] + j0q + 1)] = v1;
                }
            }
        } else if (co == kb) {                    // panel <- W rows (WT scalars)
            #pragma unroll
            for (int s2 = 0; s2 < 4; ++s2) {
                const int r = r0 + s2;
                float4 v0, v1;
                v0.x = WT[0 * PTF + r]; v0.y = WT[1 * PTF + r];
                v0.z = WT[2 * PTF + r]; v0.w = WT[3 * PTF + r];
                v1.x = WT[4 * PTF + r]; v1.y = WT[5 * PTF + r];
                v1.z = WT[6 * PTF + r]; v1.w = WT[7 * PTF + r];
                tri4[triq(roQ[s2] + j0q + 0)] = v0;
                tri4[triq(roQ[s2] + j0q + 1)] = v1;
            }
        } else {                                  // Schur: A -= W * P^T
            const int pq0 = physq(j0q) << 2, pq1 = physq(j0q + 1) << 2;
            float4 a0[4], a1[4];
            #pragma unroll
            for (int s2 = 0; s2 < 4; ++s2) {
                a0[s2] = tri4[triq(roQ[s2] + j0q + 0)];
                a1[s2] = tri4[triq(roQ[s2] + j0q + 1)];
            }
            #pragma unroll
            for (int m = 0; m < 8; ++m) {
                const float4 pa = *(const float4*)(PT + m * PTF + pq0);
                const float4 pb = *(const float4*)(PT + m * PTF + pq1);
                const float4 wq = *(const float4*)(WT + m * PTF + r0);
                a0[0].x -= wq.x * pa.x; a0[0].y -= wq.x * pa.y; a0[0].z -= wq.x * pa.z; a0[0].w -= wq.x * pa.w;
                a0[1].x -= wq.y * pa.x; a0[1].y -= wq.y * pa.y; a0[1].z -= wq.y * pa.z; a0[1].w -= wq.y * pa.w;
                a0[2].x -= wq.z * pa.x; a0[2].y -= wq.z * pa.y; a0[2].z -= wq.z * pa.z; a0[2].w -= wq.z * pa.w;
                a0[3].x -= wq.w * pa.x; a0[3].y -= wq.w * pa.y; a0[3].z -= wq.w * pa.z; a0[3].w -= wq.w * pa.w;
                a1[0].x -= wq.x * pb.x; a1[0].y -= wq.x * pb.y; a1[0].z -= wq.x * pb.z; a1[0].w -= wq.x * pb.w;
                a1[1].x -= wq.y * pb.x; a1[1].y -= wq.y * pb.y; a1[1].z -= wq.y * pb.z; a1[1].w -= wq.y * pb.w;
                a1[2].x -= wq.z * pb.x; a1[2].y -= wq.z * pb.y; a1[2].z -= wq.z * pb.z; a1[2].w -= wq.z * pb.w;
                a1[3].x -= wq.w * pb.x; a1[3].y -= wq.w * pb.y; a1[3].z -= wq.w * pb.z; a1[3].w -= wq.w * pb.w;
            }
            #pragma unroll
            for (int s2 = 0; s2 < 4; ++s2) {
                tri4[triq(roQ[s2] + j0q + 0)] = a0[s2];
                if (!top) tri4[triq(roQ[s2] + j0q + 1)] = a1[s2];
            }
        }
    };

    // --- rank-8 blocked sweep: 32 steps; tri becomes -(M^{-1}) ---
    for (int kb = 0; kb < 32; ++kb) {
        const int k0 = kb << 3;

        // phase 1: thread t = row t, full 8-wide panel snapshot -> PT
        {
            float v[8];
            if (t >= k0 + 8) {
                const float4 va = tri4[triq(roQt + (kb << 1))];
                const float4 vb = tri4[triq(roQt + (kb << 1) + 1)];
                v[0] = va.x; v[1] = va.y; v[2] = va.z; v[3] = va.w;
                v[4] = vb.x; v[5] = vb.y; v[6] = vb.z; v[7] = vb.w;
            } else {
                const int rot = rowoff(t);
                #pragma unroll
                for (int m = 0; m < 8; ++m) {
                    const int km = k0 + m;
                    v[m] = (km <= t) ? tri[triF(rot + km)] : tri[triF(rowoff(km) + t)];
                }
            }
            #pragma unroll
            for (int m = 0; m < 8; ++m) PT[m * PTF + pft] = v[m];
        }
        __syncthreads();

        // per-wave (all lanes active) register sweep of 8x8 pivot block
        float S;
        {
            const int a = lane >> 3, bb = lane & 7;
            S = PT[bb * PTF + physf(k0 + a)];
            #pragma unroll
            for (int kk = 0; kk < 8; ++kk) {
                const float dkk = __shfl(S, kk * 9);
                const float inv = 1.0f / dkk;
                const float cs  = __shfl(S, (lane & 56) | kk);
                const float rs  = __shfl(S, (kk << 3) | bb);
                const float upd = S - cs * rs * inv;
                const bool ad = (a == kk), bd = (bb == kk);
                S = (ad && bd) ? -inv : (ad ? rs * inv : (bd ? cs * inv : upd));
            }
        }
        if (t < 64) SL[(lane >> 3) * 9 + (lane & 7)] = S;   // wave 0 publishes

        // phase 2: thread t computes W[t][:] = -(P[t]·S) -> WT
        {
            float pv[8];
            #pragma unroll
            for (int m = 0; m < 8; ++m) pv[m] = PT[m * PTF + pft];
            #pragma unroll
            for (int c = 0; c < 8; ++c) {
                float acc = 0.f;
                #pragma unroll
                for (int m = 0; m < 8; ++m) acc += pv[m] * __shfl(S, (m << 3) | c);
                WT[c * PTF + t] = -acc;
            }
        }
        __syncthreads();   // SL, WT ready

        // phase 3: ~4 slabs per thread (register descriptors, independent ILP)
        update_slab(rqk[0], cok[0], kb);
        update_slab(rqk[1], cok[1], kb);
        update_slab(rqk[2], cok[2], kb);
        update_slab(rqk[3], cok[3], kb);
        if (t < 32) update_slab(rqk[4], cok[4], kb);
        __syncthreads();
    }

    // --- ADMM iterations: x = tri·vbuf (tri = -Minv, vbuf = u+p-z = -rhs) ---
    const int gb = (b << 8) + t;
    const float pi = p[gb], lbi = lb[gb], ubi = ub[gb];
    const int w = t >> 6;    // wave id = row block -> wave-uniform chunk roles

    float x = 0.f, z = 0.f, uu = 0.f;
    vbuf[t] = pi;            // it=0: z=u=0 -> vbuf = p
    __syncthreads();

    for (int it = 0; it < NITER; ++it) {
        const float* vb = vbuf + ((it & 1) << 8);
        float acc = 0.f;
        if (w == 0) acc += chunk_mixed<0>(tri, vb, t);
        else        acc += chunk_lower<0>(tri4, vb, t);
        if (w < 1)       acc += chunk_upper<64>(tri, vb, t);
        else if (w == 1) acc += chunk_mixed<64>(tri, vb, t);
        else             acc += chunk_lower<64>(tri4, vb, t);
        if (w < 2)       acc += chunk_upper<128>(tri, vb, t);
        else if (w == 2) acc += chunk_mixed<128>(tri, vb, t);
        else             acc += chunk_lower<128>(tri4, vb, t);
        if (w < 3)       acc += chunk_upper<192>(tri, vb, t);
        else             acc += chunk_mixed<192>(tri, vb, t);
        x = acc;                               // x = Minv * rhs
        const float xu = x + uu;
        z  = fminf(fmaxf(xu, lbi), ubi);
        uu = xu - z;
        vbuf[(((it + 1) & 1) << 8) + t] = (uu + pi) - z;
        __syncthreads();
    }

    out[gb] = x;
}

extern "C" void kernel_launch(void* const* d_in, const int* in_sizes, int n_in,
                              void* d_out, int out_size, void* d_ws, size_t ws_size,
                              hipStream_t stream) {
    const float* Q  = (const float*)d_in[0];
    const float* p  = (const float*)d_in[1];
    const float* lb = (const float*)d_in[2];
    const float* ub = (const float*)d_in[3];
    float* out = (float*)d_out;

    hipLaunchKernelGGL(boxqp_r9_kernel, dim3(256), dim3(NTHR), 0, stream,
                       Q, p, lb, ub, out);
}